// Round 2
// baseline (986.814 us; speedup 1.0000x reference)
//
#include <hip/hip_runtime.h>
#include <math.h>
#include <float.h>

#define D 128

// ---------------- CSR build ----------------

__global__ void count_kernel(const int* __restrict__ dst, int* __restrict__ cnt, int E) {
    int e = blockIdx.x * blockDim.x + threadIdx.x;
    if (e < E) atomicAdd(&cnt[dst[e]], 1);
}

__global__ void dinv_kernel(const int* __restrict__ cnt, float* __restrict__ dinv, int n) {
    int i = blockIdx.x * blockDim.x + threadIdx.x;
    if (i < n) dinv[i] = rsqrtf((float)cnt[i] + 1.0f);   // +1 self-loop; deg>=1 always
}

// exclusive scan of cnt -> rp, 1024 elems/block
__global__ void scan1(const int* __restrict__ cnt, int* __restrict__ rp, int* __restrict__ aux, int n) {
    __shared__ int sh[256];
    int tid = threadIdx.x;
    int base = blockIdx.x * 1024 + tid * 4;
    int v[4]; int s = 0;
#pragma unroll
    for (int i = 0; i < 4; i++) { int idx = base + i; int t = (idx < n) ? cnt[idx] : 0; v[i] = s; s += t; }
    sh[tid] = s; __syncthreads();
    for (int off = 1; off < 256; off <<= 1) {
        int t = (tid >= off) ? sh[tid - off] : 0;
        __syncthreads();
        sh[tid] += t;
        __syncthreads();
    }
    int excl = sh[tid] - s;
#pragma unroll
    for (int i = 0; i < 4; i++) { int idx = base + i; if (idx < n) rp[idx] = excl + v[i]; }
    if (tid == 255) aux[blockIdx.x] = sh[255];
}

__global__ void scan2(int* aux, int nb) {
    __shared__ int sh[256];
    int tid = threadIdx.x;
    int v = (tid < nb) ? aux[tid] : 0;
    sh[tid] = v; __syncthreads();
    for (int off = 1; off < 256; off <<= 1) {
        int t = (tid >= off) ? sh[tid - off] : 0;
        __syncthreads();
        sh[tid] += t;
        __syncthreads();
    }
    if (tid < nb) aux[tid] = sh[tid] - v;   // exclusive
}

__global__ void scan3(int* __restrict__ rp, const int* __restrict__ aux, int n, int E) {
    int base = blockIdx.x * 1024;
    int add = aux[blockIdx.x];
    for (int i = threadIdx.x; i < 1024; i += 256) {
        int idx = base + i;
        if (idx < n) rp[idx] += add;
    }
    if (blockIdx.x == 0 && threadIdx.x == 0) rp[n] = E;
}

__global__ void fill_kernel(const int* __restrict__ src, const int* __restrict__ dst,
                            const int* __restrict__ rp, int* __restrict__ tmp,
                            int* __restrict__ csr_src, int E) {
    int e = blockIdx.x * blockDim.x + threadIdx.x;
    if (e >= E) return;
    int d = dst[e];
    int pos = rp[d] + atomicAdd(&tmp[d], 1);
    csr_src[pos] = src[e];
}

// ---------------- dense GEMM: out[n][128] = A[n][128] @ Wt[128][128] ----------------
#define BM 64
#define BK 32
__global__ __launch_bounds__(256) void gemm128(const float* __restrict__ A,
                                               const float* __restrict__ Wt,
                                               float* __restrict__ out, int n) {
    __shared__ float As[BM][BK];
    __shared__ float Ws[BK][D];
    const int tid = threadIdx.x;
    const int row0 = blockIdx.x * BM;
    const int r0 = (tid >> 5) * 8;       // 8 rows per thread
    const int c0 = (tid & 31) * 4;       // 4 cols per thread
    float4 acc[8];
#pragma unroll
    for (int i = 0; i < 8; i++) acc[i] = make_float4(0.f, 0.f, 0.f, 0.f);

    for (int k0 = 0; k0 < D; k0 += BK) {
        // stage A tile: 64x32 floats = 512 float4
#pragma unroll
        for (int i = 0; i < 2; ++i) {
            int f4 = tid + i * 256;          // 0..511
            int r = f4 >> 3;                 // 8 float4 per row
            int kk = (f4 & 7) << 2;
            float4 v = make_float4(0.f, 0.f, 0.f, 0.f);
            if (row0 + r < n) v = *(const float4*)&A[(size_t)(row0 + r) * D + k0 + kk];
            *(float4*)&As[r][kk] = v;
        }
        // stage W tile: 32x128 floats = 1024 float4
#pragma unroll
        for (int i = 0; i < 4; ++i) {
            int f4 = tid + i * 256;          // 0..1023
            int r = f4 >> 5;                 // 32 float4 per row
            int c = (f4 & 31) << 2;
            *(float4*)&Ws[r][c] = *(const float4*)&Wt[(size_t)(k0 + r) * D + c];
        }
        __syncthreads();
#pragma unroll
        for (int kk = 0; kk < BK; ++kk) {
            float4 bv = *(const float4*)&Ws[kk][c0];
#pragma unroll
            for (int i = 0; i < 8; ++i) {
                float a = As[r0 + i][kk];
                acc[i].x += a * bv.x; acc[i].y += a * bv.y;
                acc[i].z += a * bv.z; acc[i].w += a * bv.w;
            }
        }
        __syncthreads();
    }
#pragma unroll
    for (int i = 0; i < 8; ++i) {
        int r = row0 + r0 + i;
        if (r < n) *(float4*)&out[(size_t)r * D + c0] = acc[i];
    }
}

// ---------------- fused aggregation + bias + BN + ReLU ----------------
__global__ __launch_bounds__(128) void agg_kernel(const float* __restrict__ m,
                                                  const int* __restrict__ rp,
                                                  const int* __restrict__ csr_src,
                                                  const float* __restrict__ dinv,
                                                  const float* __restrict__ bias,
                                                  const float* __restrict__ gamma,
                                                  const float* __restrict__ beta,
                                                  const float* __restrict__ rmean,
                                                  const float* __restrict__ rvar,
                                                  float* __restrict__ hout, int n) {
    int row = blockIdx.x;
    if (row >= n) return;
    int d = threadIdx.x;
    float di = dinv[row];
    float acc = m[(size_t)row * D + d] * di * di;     // self loop
    int beg = rp[row], end = rp[row + 1];
    for (int e = beg; e < end; ++e) {
        int s = csr_src[e];
        float w = dinv[s] * di;
        acc += m[(size_t)s * D + d] * w;
    }
    float inv = rsqrtf(rvar[d] + 1e-5f);
    float v = (acc + bias[d] - rmean[d]) * inv * gamma[d] + beta[d];
    hout[(size_t)row * D + d] = fmaxf(v, 0.f);
}

// ---------------- pooling ----------------
__global__ void bounds_kernel(const int* __restrict__ batch, int* __restrict__ gstart, int n, int G) {
    int i = blockIdx.x * blockDim.x + threadIdx.x;
    if (i >= n) return;
    int g = batch[i];
    int gp = (i == 0) ? -1 : batch[i - 1];
    for (int gg = gp + 1; gg <= g; ++gg) gstart[gg] = i;
    if (i == n - 1) for (int gg = g + 1; gg <= G; ++gg) gstart[gg] = n;
}

__global__ __launch_bounds__(128) void pool_kernel(const float* __restrict__ h,
                                                   const int* __restrict__ gstart,
                                                   float* __restrict__ out) {
    int g = blockIdx.x;
    int d = threadIdx.x;
    int beg = gstart[g], end = gstart[g + 1];
    float s = 0.f;
    float mx = -INFINITY;
    for (int i = beg; i < end; ++i) {
        float v = h[(size_t)i * D + d];
        s += v;
        mx = fmaxf(mx, v);
    }
    float cnt = (float)(end - beg);
    out[g * (2 * D) + d] = s / fmaxf(cnt, 1.0f);
    out[g * (2 * D) + D + d] = mx;
}

// ---------------- launch ----------------
extern "C" void kernel_launch(void* const* d_in, const int* in_sizes, int n_in,
                              void* d_out, int out_size, void* d_ws, size_t ws_size,
                              hipStream_t stream) {
    const float* x     = (const float*)d_in[0];
    const float* W     = (const float*)d_in[1];
    const float* b     = (const float*)d_in[2];
    const float* gamma = (const float*)d_in[3];
    const float* beta  = (const float*)d_in[4];
    const float* rmean = (const float*)d_in[5];
    const float* rvar  = (const float*)d_in[6];
    const int*   eidx  = (const int*)d_in[7];
    const int*   batch = (const int*)d_in[8];

    const int N = in_sizes[8];
    const int E = in_sizes[7] / 2;
    const int L = in_sizes[2] / D;
    const int G = out_size / (2 * D);

    const int* esrc = eidx;
    const int* edst = eidx + E;

    // ws carve-up (256B aligned)
    size_t off = 0;
    auto carve = [&](size_t bytes) { size_t cur = off; off += (bytes + 255) & ~(size_t)255; return cur; };
    char* base = (char*)d_ws;
    const int nb = (N + 1023) / 1024;           // scan blocks (<=256 for N<=262144)

    int*   cnt   = (int*)  (base + carve((size_t)N * 4));
    int*   tmp   = (int*)  (base + carve((size_t)N * 4));
    int*   rp    = (int*)  (base + carve((size_t)(N + 1) * 4));
    int*   aux   = (int*)  (base + carve((size_t)nb * 4));
    float* dinv  = (float*)(base + carve((size_t)N * 4));
    int*   csr   = (int*)  (base + carve((size_t)E * 4));
    float* hbuf  = (float*)(base + carve((size_t)N * D * 4));
    float* mbuf  = (float*)(base + carve((size_t)N * D * 4));
    int*   gst   = (int*)  (base + carve((size_t)(G + 1) * 4));
    (void)ws_size;

    hipMemsetAsync(cnt, 0, (size_t)N * 4, stream);
    hipMemsetAsync(tmp, 0, (size_t)N * 4, stream);

    int eb = (E + 255) / 256;
    int nbN = (N + 255) / 256;

    count_kernel<<<eb, 256, 0, stream>>>(edst, cnt, E);
    dinv_kernel<<<nbN, 256, 0, stream>>>(cnt, dinv, N);
    scan1<<<nb, 256, 0, stream>>>(cnt, rp, aux, N);
    scan2<<<1, 256, 0, stream>>>(aux, nb);
    scan3<<<nb, 256, 0, stream>>>(rp, aux, N, E);
    fill_kernel<<<eb, 256, 0, stream>>>(esrc, edst, rp, tmp, csr, E);

    int gemmb = (N + BM - 1) / BM;
    for (int l = 0; l < L; ++l) {
        const float* hin = (l == 0) ? x : hbuf;
        gemm128<<<gemmb, 256, 0, stream>>>(hin, W + (size_t)l * D * D, mbuf, N);
        agg_kernel<<<N, 128, 0, stream>>>(mbuf, rp, csr, dinv,
                                          b + l * D, gamma + l * D, beta + l * D,
                                          rmean + l * D, rvar + l * D, hbuf, N);
    }

    bounds_kernel<<<nbN, 256, 0, stream>>>(batch, gst, N, G);
    pool_kernel<<<G, 128, 0, stream>>>(hbuf, gst, (float*)d_out);
}

// Round 4
// 512.936 us; speedup vs baseline: 1.9239x; 1.9239x over previous
//
#include <hip/hip_runtime.h>
#include <math.h>
#include <float.h>

#define D 128

typedef short short8 __attribute__((ext_vector_type(8)));
typedef float f32x4 __attribute__((ext_vector_type(4)));

__device__ __forceinline__ unsigned int bf16r(float f) {
    unsigned int u = __float_as_uint(f);
    return (u + 0x7fffu + ((u >> 16) & 1u)) >> 16;   // RNE
}
__device__ __forceinline__ float bf2f(unsigned int lo16) {
    return __uint_as_float(lo16 << 16);
}

// ---------------- CSR build ----------------

__global__ void count_kernel(const int* __restrict__ dst, int* __restrict__ cnt, int E) {
    int e = blockIdx.x * blockDim.x + threadIdx.x;
    if (e < E) atomicAdd(&cnt[dst[e]], 1);
}

__global__ void dinv_kernel(const int* __restrict__ cnt, float* __restrict__ dinv, int n) {
    int i = blockIdx.x * blockDim.x + threadIdx.x;
    if (i < n) dinv[i] = rsqrtf((float)cnt[i] + 1.0f);   // +1 self-loop
}

__global__ void scan1(const int* __restrict__ cnt, int* __restrict__ rp, int* __restrict__ aux, int n) {
    __shared__ int sh[256];
    int tid = threadIdx.x;
    int base = blockIdx.x * 1024 + tid * 4;
    int v[4]; int s = 0;
#pragma unroll
    for (int i = 0; i < 4; i++) { int idx = base + i; int t = (idx < n) ? cnt[idx] : 0; v[i] = s; s += t; }
    sh[tid] = s; __syncthreads();
    for (int off = 1; off < 256; off <<= 1) {
        int t = (tid >= off) ? sh[tid - off] : 0;
        __syncthreads();
        sh[tid] += t;
        __syncthreads();
    }
    int excl = sh[tid] - s;
#pragma unroll
    for (int i = 0; i < 4; i++) { int idx = base + i; if (idx < n) rp[idx] = excl + v[i]; }
    if (tid == 255) aux[blockIdx.x] = sh[255];
}

__global__ void scan2(int* aux, int nb) {
    __shared__ int sh[256];
    int tid = threadIdx.x;
    int v = (tid < nb) ? aux[tid] : 0;
    sh[tid] = v; __syncthreads();
    for (int off = 1; off < 256; off <<= 1) {
        int t = (tid >= off) ? sh[tid - off] : 0;
        __syncthreads();
        sh[tid] += t;
        __syncthreads();
    }
    if (tid < nb) aux[tid] = sh[tid] - v;   // exclusive
}

__global__ void scan3(int* __restrict__ rp, const int* __restrict__ aux, int n, int E) {
    int base = blockIdx.x * 1024;
    int add = aux[blockIdx.x];
    for (int i = threadIdx.x; i < 1024; i += 256) {
        int idx = base + i;
        if (idx < n) rp[idx] += add;
    }
    if (blockIdx.x == 0 && threadIdx.x == 0) rp[n] = E;
}

__global__ void fill_kernel(const int* __restrict__ src, const int* __restrict__ dst,
                            const int* __restrict__ rp, int* __restrict__ tmp,
                            const float* __restrict__ dinv,
                            int* __restrict__ csr_src, float* __restrict__ wgt, int E) {
    int e = blockIdx.x * blockDim.x + threadIdx.x;
    if (e >= E) return;
    int d = dst[e], s = src[e];
    int pos = rp[d] + atomicAdd(&tmp[d], 1);
    csr_src[pos] = s;
    wgt[pos] = dinv[s] * dinv[d];
}

// ---------------- prep: x -> bf16, W transpose -> bf16, BN fold ----------------

__global__ void cvt_kernel(const float* __restrict__ x, unsigned int* __restrict__ xb, int n2) {
    int i = blockIdx.x * blockDim.x + threadIdx.x;
    if (i < n2) {
        float2 v = *(const float2*)&x[(size_t)i * 2];
        xb[i] = bf16r(v.x) | (bf16r(v.y) << 16);
    }
}

__global__ void wprep_kernel(const float* __restrict__ W, const float* __restrict__ b,
                             const float* __restrict__ gamma, const float* __restrict__ beta,
                             const float* __restrict__ rmean, const float* __restrict__ rvar,
                             unsigned short* __restrict__ Wt, float* __restrict__ sc,
                             float* __restrict__ sh, int L_) {
    int t = blockIdx.x * blockDim.x + threadIdx.x;
    int total = L_ * D * D;
    if (t < total) {
        int l = t / (D * D), rem = t % (D * D);
        int r = rem >> 7, k = rem & 127;              // Wt[l][r][k] = W[l][k][r]
        Wt[t] = (unsigned short)bf16r(W[l * D * D + k * D + r]);
    }
    if (t < L_ * D) {
        float inv = rsqrtf(rvar[t] + 1e-5f);
        float s = inv * gamma[t];
        sc[t] = s;
        sh[t] = (b[t] - rmean[t]) * s + beta[t];
    }
}

// ---------------- MFMA bf16 GEMM: m[n][128] = h[n][128] @ W  (via Wt) ----------------
// x-frag = Wt row (feature f), y-frag = h row (node). D[i][j] = m[node j][feature i].
#define GBM 64
__global__ __launch_bounds__(256) void gemm_mfma(const unsigned short* __restrict__ hin,
                                                 const unsigned short* __restrict__ Wt,
                                                 unsigned short* __restrict__ mout, int n) {
    __shared__ short Ah[GBM * 136];      // 64 rows x 128 bf16, padded to 136
    __shared__ short Wl[D * 136];        // 128 rows x 128 bf16, padded
    const int tid = threadIdx.x;
    const int row0 = blockIdx.x * GBM;

    // stage A tile (64x128 bf16): 1024 chunks of 8 bf16 (16 chunks/row)
#pragma unroll
    for (int i = 0; i < 4; ++i) {
        int c = tid + i * 256;               // 0..1023
        int r = c >> 4, ck = (c & 15) * 8;
        int4 v = make_int4(0, 0, 0, 0);
        int grow = row0 + r;
        if (grow < n) v = *(const int4*)&hin[(size_t)grow * D + ck];
        *(int4*)&Ah[r * 136 + ck] = v;
    }
    // stage Wt (128x128 bf16): 2048 chunks
#pragma unroll
    for (int i = 0; i < 8; ++i) {
        int c = tid + i * 256;               // 0..2047
        int r = c >> 4, ck = (c & 15) * 8;
        *(int4*)&Wl[r * 136 + ck] = *(const int4*)&Wt[(size_t)r * D + ck];
    }
    __syncthreads();

    const int wid = tid >> 6;          // wave 0..3 -> nodes [wid*16, wid*16+16)
    const int lane = tid & 63;
    const int lr = lane & 15;
    const int lg = lane >> 4;

    f32x4 acc[8];
#pragma unroll
    for (int fc = 0; fc < 8; ++fc) acc[fc] = (f32x4){0.f, 0.f, 0.f, 0.f};

#pragma unroll
    for (int ks = 0; ks < 4; ++ks) {
        int kb = ks * 32 + lg * 8;
        short8 y = *(const short8*)&Ah[(wid * 16 + lr) * 136 + kb];
#pragma unroll
        for (int fc = 0; fc < 8; ++fc) {
            short8 x = *(const short8*)&Wl[(fc * 16 + lr) * 136 + kb];
            acc[fc] = __builtin_amdgcn_mfma_f32_16x16x32_bf16(x, y, acc[fc], 0, 0, 0);
        }
    }

    int grow = row0 + wid * 16 + lr;
    if (grow < n) {
#pragma unroll
        for (int fc = 0; fc < 8; ++fc) {
            int gcol = fc * 16 + lg * 4;
            uint2 pk;
            pk.x = bf16r(acc[fc][0]) | (bf16r(acc[fc][1]) << 16);
            pk.y = bf16r(acc[fc][2]) | (bf16r(acc[fc][3]) << 16);
            *(uint2*)&mout[(size_t)grow * D + gcol] = pk;
        }
    }
}

// ---------------- fused aggregation + bias + BN + ReLU (bf16 in/out, f32 acc) ----------------
__global__ __launch_bounds__(256) void agg_bf16(const unsigned int* __restrict__ M,
                                                const int* __restrict__ rp,
                                                const int* __restrict__ csr_src,
                                                const float* __restrict__ wgt,
                                                const float* __restrict__ dinv,
                                                const float* __restrict__ sc,
                                                const float* __restrict__ sh,
                                                unsigned int* __restrict__ H, int n) {
    const int wid = threadIdx.x >> 6;
    const int lane = threadIdx.x & 63;
    const int row = blockIdx.x * 4 + wid;
    if (row >= n) return;

    float di = dinv[row];
    float dw = di * di;
    unsigned int u = M[(size_t)row * 64 + lane];
    float a0 = bf2f(u & 0xffffu) * dw;
    float a1 = bf2f(u >> 16) * dw;

    int e = rp[row], end = rp[row + 1];
    for (; e + 4 <= end; e += 4) {
        int s0 = csr_src[e], s1 = csr_src[e + 1], s2 = csr_src[e + 2], s3 = csr_src[e + 3];
        float w0 = wgt[e], w1 = wgt[e + 1], w2 = wgt[e + 2], w3 = wgt[e + 3];
        unsigned int u0 = M[(size_t)s0 * 64 + lane];
        unsigned int u1 = M[(size_t)s1 * 64 + lane];
        unsigned int u2 = M[(size_t)s2 * 64 + lane];
        unsigned int u3 = M[(size_t)s3 * 64 + lane];
        a0 += w0 * bf2f(u0 & 0xffffu) + w1 * bf2f(u1 & 0xffffu)
            + w2 * bf2f(u2 & 0xffffu) + w3 * bf2f(u3 & 0xffffu);
        a1 += w0 * bf2f(u0 >> 16) + w1 * bf2f(u1 >> 16)
            + w2 * bf2f(u2 >> 16) + w3 * bf2f(u3 >> 16);
    }
    for (; e < end; ++e) {
        int s = csr_src[e];
        float w = wgt[e];
        unsigned int us = M[(size_t)s * 64 + lane];
        a0 += w * bf2f(us & 0xffffu);
        a1 += w * bf2f(us >> 16);
    }

    int c0 = lane * 2;
    float v0 = fmaxf(a0 * sc[c0] + sh[c0], 0.f);
    float v1 = fmaxf(a1 * sc[c0 + 1] + sh[c0 + 1], 0.f);
    H[(size_t)row * 64 + lane] = bf16r(v0) | (bf16r(v1) << 16);
}

// ---------------- pooling ----------------
__global__ void bounds_kernel(const int* __restrict__ batch, int* __restrict__ gstart, int n, int G) {
    int i = blockIdx.x * blockDim.x + threadIdx.x;
    if (i >= n) return;
    int g = batch[i];
    int gp = (i == 0) ? -1 : batch[i - 1];
    for (int gg = gp + 1; gg <= g; ++gg) gstart[gg] = i;
    if (i == n - 1) for (int gg = g + 1; gg <= G; ++gg) gstart[gg] = n;
}

__global__ __launch_bounds__(64) void pool_bf16(const unsigned int* __restrict__ H,
                                                const int* __restrict__ gstart,
                                                float* __restrict__ out) {
    int g = blockIdx.x;
    int lane = threadIdx.x;
    int beg = gstart[g], end = gstart[g + 1];
    float s0 = 0.f, s1 = 0.f, m0 = -INFINITY, m1 = -INFINITY;
    int i = beg;
    for (; i + 2 <= end; i += 2) {
        unsigned int ua = H[(size_t)i * 64 + lane];
        unsigned int ub = H[(size_t)(i + 1) * 64 + lane];
        float a0 = bf2f(ua & 0xffffu), a1 = bf2f(ua >> 16);
        float b0 = bf2f(ub & 0xffffu), b1 = bf2f(ub >> 16);
        s0 += a0 + b0; s1 += a1 + b1;
        m0 = fmaxf(m0, fmaxf(a0, b0)); m1 = fmaxf(m1, fmaxf(a1, b1));
    }
    for (; i < end; ++i) {
        unsigned int ua = H[(size_t)i * 64 + lane];
        float a0 = bf2f(ua & 0xffffu), a1 = bf2f(ua >> 16);
        s0 += a0; s1 += a1;
        m0 = fmaxf(m0, a0); m1 = fmaxf(m1, a1);
    }
    float cnt = fmaxf((float)(end - beg), 1.0f);
    int c = lane * 2;
    out[g * (2 * D) + c] = s0 / cnt;
    out[g * (2 * D) + c + 1] = s1 / cnt;
    out[g * (2 * D) + D + c] = m0;
    out[g * (2 * D) + D + c + 1] = m1;
}

// ---------------- launch ----------------
extern "C" void kernel_launch(void* const* d_in, const int* in_sizes, int n_in,
                              void* d_out, int out_size, void* d_ws, size_t ws_size,
                              hipStream_t stream) {
    const float* x     = (const float*)d_in[0];
    const float* W     = (const float*)d_in[1];
    const float* b     = (const float*)d_in[2];
    const float* gamma = (const float*)d_in[3];
    const float* beta  = (const float*)d_in[4];
    const float* rmean = (const float*)d_in[5];
    const float* rvar  = (const float*)d_in[6];
    const int*   eidx  = (const int*)d_in[7];
    const int*   batch = (const int*)d_in[8];

    const int N = in_sizes[8];
    const int E = in_sizes[7] / 2;
    const int L = in_sizes[2] / D;
    const int G = out_size / (2 * D);

    const int* esrc = eidx;
    const int* edst = eidx + E;

    size_t off = 0;
    auto carve = [&](size_t bytes) { size_t cur = off; off += (bytes + 255) & ~(size_t)255; return cur; };
    char* base = (char*)d_ws;
    const int nb = (N + 1023) / 1024;

    int*            cnt  = (int*)           (base + carve((size_t)N * 4));
    int*            tmp  = (int*)           (base + carve((size_t)N * 4));
    int*            rp   = (int*)           (base + carve((size_t)(N + 1) * 4));
    int*            aux  = (int*)           (base + carve((size_t)nb * 4));
    float*          dinv = (float*)         (base + carve((size_t)N * 4));
    int*            csr  = (int*)           (base + carve((size_t)E * 4));
    float*          wgt  = (float*)         (base + carve((size_t)E * 4));
    unsigned short* xb   = (unsigned short*)(base + carve((size_t)N * D * 2));
    unsigned short* hbuf = (unsigned short*)(base + carve((size_t)N * D * 2));
    unsigned short* mbuf = (unsigned short*)(base + carve((size_t)N * D * 2));
    unsigned short* Wt   = (unsigned short*)(base + carve((size_t)L * D * D * 2));
    float*          sc   = (float*)         (base + carve((size_t)L * D * 4));
    float*          shb  = (float*)         (base + carve((size_t)L * D * 4));
    int*            gst  = (int*)           (base + carve((size_t)(G + 1) * 4));
    (void)ws_size;

    hipMemsetAsync(cnt, 0, (size_t)N * 4, stream);
    hipMemsetAsync(tmp, 0, (size_t)N * 4, stream);

    int eb = (E + 255) / 256;
    int nbN = (N + 255) / 256;

    count_kernel<<<eb, 256, 0, stream>>>(edst, cnt, E);
    dinv_kernel<<<nbN, 256, 0, stream>>>(cnt, dinv, N);
    scan1<<<nb, 256, 0, stream>>>(cnt, rp, aux, N);
    scan2<<<1, 256, 0, stream>>>(aux, nb);
    scan3<<<nb, 256, 0, stream>>>(rp, aux, N, E);
    fill_kernel<<<eb, 256, 0, stream>>>(esrc, edst, rp, tmp, dinv, csr, wgt, E);

    int n2 = N * (D / 2);
    cvt_kernel<<<(n2 + 255) / 256, 256, 0, stream>>>(x, (unsigned int*)xb, n2);
    wprep_kernel<<<(L * D * D + 255) / 256, 256, 0, stream>>>(W, b, gamma, beta, rmean, rvar,
                                                              Wt, sc, shb, L);

    int gemmb = (N + GBM - 1) / GBM;
    int aggb = (N + 3) / 4;
    for (int l = 0; l < L; ++l) {
        const unsigned short* hin = (l == 0) ? xb : hbuf;
        gemm_mfma<<<gemmb, 256, 0, stream>>>(hin, Wt + (size_t)l * D * D, mbuf, N);
        agg_bf16<<<aggb, 256, 0, stream>>>((const unsigned int*)mbuf, rp, csr, wgt, dinv,
                                           sc + l * D, shb + l * D,
                                           (unsigned int*)hbuf, N);
    }

    bounds_kernel<<<nbN, 256, 0, stream>>>(batch, gst, N, G);
    pool_bf16<<<G, 64, 0, stream>>>((const unsigned int*)hbuf, gst, (float*)d_out);
}